// Round 4
// baseline (173.683 us; speedup 1.0000x reference)
//
#include <hip/hip_runtime.h>
#include <hip/hip_bf16.h>
#include <cstdint>

// Problem constants
#define NPTS  131072
#define NRET  65536
#define NBAT  64
#define NBUCK (1 << 18)   // buckets = top-18 bits of descending key
#define BSH   14          // d >> 14 -> bucket

// Monotone map f32 -> u32 such that ascending u32 == DESCENDING float value.
__device__ __forceinline__ unsigned int desc_key(float w) {
    unsigned int b = __float_as_uint(w);
    unsigned int s = b ^ ((unsigned int)((int)b >> 31) | 0x80000000u); // ascending
    return ~s;                                                        // descending
}

// Zero 2 MiB (hist + cnt) with uint4 stores: 512 blocks x 256 threads x 16 B.
__global__ void k_zero(uint4* __restrict__ p) {
    int t = blockIdx.x * 256 + threadIdx.x;
    p[t] = make_uint4(0u, 0u, 0u, 0u);
}

// ---------- max reduction (exact, order-independent) ----------
__global__ void k_pmax(const float* __restrict__ w, float* __restrict__ pmax) {
    __shared__ float sm[256];
    int tid = threadIdx.x;
    float m = -3.402823466e38f;
    for (int i = blockIdx.x * 256 + tid; i < NPTS; i += gridDim.x * 256)
        m = fmaxf(m, w[i]);
    sm[tid] = m; __syncthreads();
    for (int off = 128; off > 0; off >>= 1) {
        if (tid < off) sm[tid] = fmaxf(sm[tid], sm[tid + off]);
        __syncthreads();
    }
    if (tid == 0) pmax[blockIdx.x] = sm[0];
}

__global__ void k_fmax(const float* __restrict__ pmax, float* __restrict__ scal) {
    __shared__ float sm[256];
    int tid = threadIdx.x;
    sm[tid] = pmax[tid]; __syncthreads();
    for (int off = 128; off > 0; off >>= 1) {
        if (tid < off) sm[tid] = fmaxf(sm[tid], sm[tid + off]);
        __syncthreads();
    }
    if (tid == 0) scal[0] = sm[0];
}

// e_i = correctly-rounded f32 exp(f32(w_i - m)) via double; fused numpy base-128
// pairwise partial sum (8 interleaved accumulators, numpy's combine order).
__global__ void k_exp_sum(const float* __restrict__ w, const float* __restrict__ scal,
                          float* __restrict__ e_out, float* __restrict__ bs) {
    int t = blockIdx.x * 256 + threadIdx.x;       // 0..1023, 128 elems each
    const float* wp = w + (size_t)t * 128;
    float* ep = e_out + (size_t)t * 128;
    float m = scal[0];
    float r[8];
    #pragma unroll
    for (int k = 0; k < 8; ++k) {
        float e = (float)exp((double)(wp[k] - m));
        ep[k] = e; r[k] = e;
    }
    for (int i = 8; i < 128; i += 8) {
        #pragma unroll
        for (int k = 0; k < 8; ++k) {
            float e = (float)exp((double)(wp[i + k] - m));
            ep[i + k] = e; r[k] += e;
        }
    }
    bs[t] = ((r[0]+r[1])+(r[2]+r[3]))+((r[4]+r[5])+(r[6]+r[7]));
}

// Perfect binary combine tree over 1024 base sums (numpy's recursion shape).
// mode 0: dst = sum ; mode 1: dst = 1/(sum + 1e-6)
__global__ void k_tree(const float* __restrict__ bs, float* __restrict__ dst, int mode) {
    __shared__ float sm[1024];
    int tid = threadIdx.x;
    sm[tid] = bs[tid]; __syncthreads();
    for (int n = 512; n >= 1; n >>= 1) {
        float v = 0.0f;
        if (tid < n) v = sm[2*tid] + sm[2*tid+1];
        __syncthreads();
        if (tid < n) sm[tid] = v;
        __syncthreads();
    }
    if (tid == 0) dst[0] = mode ? (1.0f / (sm[0] + 1e-6f)) : sm[0];
}

// p_i = e_i / Z (IEEE f32 div, matches np); histogram; fused base-128 sum of p.
__global__ void k_prob_hist_sum(float* __restrict__ probs, const float* __restrict__ scal,
                                unsigned int* __restrict__ hist, float* __restrict__ bs2) {
    int t = blockIdx.x * 256 + threadIdx.x;       // 0..1023, 128 elems each
    float* pp = probs + (size_t)t * 128;
    float Z = scal[1];
    float r[8];
    #pragma unroll
    for (int k = 0; k < 8; ++k) {
        float pv = pp[k] / Z;
        pp[k] = pv; r[k] = pv;
        atomicAdd(&hist[desc_key(pv) >> BSH], 1u);
    }
    for (int i = 8; i < 128; i += 8) {
        #pragma unroll
        for (int k = 0; k < 8; ++k) {
            float pv = pp[i + k] / Z;
            pp[i + k] = pv; r[k] += pv;
            atomicAdd(&hist[desc_key(pv) >> BSH], 1u);
        }
    }
    bs2[t] = ((r[0]+r[1])+(r[2]+r[3]))+((r[4]+r[5])+(r[6]+r[7]));
}

// ---------- bucket ranking sort ----------
__global__ void k_scan_local(const unsigned int* __restrict__ hist,
                             unsigned int* __restrict__ local,
                             unsigned int* __restrict__ chunksum) {
    __shared__ unsigned int sm[1024];
    int tid = threadIdx.x;
    int g = blockIdx.x * 1024 + tid;
    unsigned int v = hist[g];
    sm[tid] = v; __syncthreads();
    for (int off = 1; off < 1024; off <<= 1) {
        unsigned int t = (tid >= off) ? sm[tid - off] : 0u;
        __syncthreads();
        sm[tid] += t;
        __syncthreads();
    }
    local[g] = sm[tid] - v;                  // exclusive within chunk
    if (tid == 1023) chunksum[blockIdx.x] = sm[1023];
}

__global__ void k_scan_chunk(const unsigned int* __restrict__ chunksum,
                             unsigned int* __restrict__ chunkoff) {
    __shared__ unsigned int sm[256];
    int tid = threadIdx.x;
    unsigned int v = chunksum[tid];
    sm[tid] = v; __syncthreads();
    for (int off = 1; off < 256; off <<= 1) {
        unsigned int t = (tid >= off) ? sm[tid - off] : 0u;
        __syncthreads();
        sm[tid] += t;
        __syncthreads();
    }
    chunkoff[tid] = sm[tid] - v;
}

// Scatter unique key (desc_prob_bits<<17)|idx into its bucket segment.
__global__ void k_scatter(const float* __restrict__ probs,
                          const unsigned int* __restrict__ local,
                          const unsigned int* __restrict__ chunkoff,
                          unsigned int* __restrict__ cnt,
                          unsigned long long* __restrict__ bucketed) {
    int i = blockIdx.x * 256 + threadIdx.x;
    unsigned int d = desc_key(probs[i]);
    unsigned int b = d >> BSH;
    unsigned int base = chunkoff[b >> 10] + local[b];
    unsigned int off = atomicAdd(&cnt[b], 1u);
    bucketed[base + off] = ((unsigned long long)d << 17) | (unsigned int)i;
}

// Exact global rank = bucket base + (# strictly smaller keys in bucket).
// Keys unique -> permutation -> deterministic. Equal probs order index-asc.
// Stores, per SOURCE index i: its rank and premultiplied scale.
__global__ void k_rank(const unsigned long long* __restrict__ bucketed,
                       const unsigned int* __restrict__ hist,
                       const unsigned int* __restrict__ local,
                       const unsigned int* __restrict__ chunkoff,
                       const float* __restrict__ probs,
                       const float* __restrict__ scal,
                       uint2* __restrict__ rankscale) {
    int p = blockIdx.x * 256 + threadIdx.x;
    unsigned long long kk = bucketed[p];
    unsigned int b = (unsigned int)(kk >> 31);        // (d<<17)>>31 == d>>14
    unsigned int start = chunkoff[b >> 10] + local[b];
    unsigned int len = hist[b];
    unsigned int c = 0;
    for (unsigned int q = start; q < start + len; ++q)
        c += (bucketed[q] < kk) ? 1u : 0u;
    unsigned int rank = start + c;
    unsigned int i = (unsigned int)(kk & 0x1FFFFu);
    float s = probs[i] * scal[2];
    rankscale[i] = make_uint2(rank, __float_as_uint(s));
}

// ---------- permutation copy: coalesced READ, L2-resident scatter WRITE ----------
// block j -> xcd v=j&7, slot s=j>>3; batch b = v + 8*(s>>9); src block = s&511.
// Each XCD processes its 8 batches consecutively; per-batch write window is
// 1 MiB (out[b]) -> stays L2-resident so random 16 B writes merge into full
// lines before eviction. Reads of pts are fully coalesced.
__global__ void k_perm(const float4* __restrict__ pts,
                       const uint2* __restrict__ rankscale,
                       float4* __restrict__ out) {
    int j = blockIdx.x;
    int v = j & 7;
    int s = j >> 3;
    int b = v + ((s >> 9) << 3);
    int i = ((s & 511) << 8) + threadIdx.x;    // source row, coalesced
    uint2 rs = rankscale[i];
    if (rs.x < NRET) {
        float sc = __uint_as_float(rs.y);
        float4 val = pts[(size_t)b * NPTS + i];
        val.x *= sc; val.y *= sc; val.z *= sc; val.w *= sc;
        out[(size_t)b * NRET + rs.x] = val;
    }
}

extern "C" void kernel_launch(void* const* d_in, const int* in_sizes, int n_in,
                              void* d_out, int out_size, void* d_ws, size_t ws_size,
                              hipStream_t stream) {
    const float* pts = (const float*)d_in[0];   // [64, 131072, 4]
    const float* w   = (const float*)d_in[1];   // [131072]
    float* out = (float*)d_out;

    char* ws = (char*)d_ws;
    unsigned int* hist      = (unsigned int*)(ws + 0);                 // 1 MB
    unsigned int* cnt       = (unsigned int*)(ws + (1 << 20));         // 1 MB
    unsigned int* local     = (unsigned int*)(ws + (2 << 20));         // 1 MB
    unsigned int* chunksum  = (unsigned int*)(ws + (3 << 20));         // 1 KB
    unsigned int* chunkoff  = (unsigned int*)(ws + (3 << 20) + 4096);  // 1 KB
    float*        pmax      = (float*)(ws + (3 << 20) + 8192);         // 1 KB
    float*        scal      = (float*)(ws + (3 << 20) + 12288);        // m, Z, inv
    float*        bs        = (float*)(ws + (3 << 20) + 16384);        // 4 KB
    float*        bs2       = (float*)(ws + (3 << 20) + 24576);        // 4 KB
    float*        probs     = (float*)(ws + (3 << 20) + (1 << 19));    // 512 KB @3.5MB
    unsigned long long* bucketed = (unsigned long long*)(ws + (4 << 20)); // 1 MB
    uint2*        rankscale = (uint2*)(ws + (5 << 20));                // 1 MB

    k_zero          <<<512, 256, 0, stream>>>((uint4*)ws);           // hist + cnt
    k_pmax          <<<256, 256, 0, stream>>>(w, pmax);
    k_fmax          <<<1,   256, 0, stream>>>(pmax, scal);
    k_exp_sum       <<<4,   256, 0, stream>>>(w, scal, probs, bs);   // probs = e
    k_tree          <<<1,  1024, 0, stream>>>(bs, &scal[1], 0);      // Z
    k_prob_hist_sum <<<4,   256, 0, stream>>>(probs, scal, hist, bs2); // probs = p
    k_tree          <<<1,  1024, 0, stream>>>(bs2, &scal[2], 1);     // 1/(S+1e-6)
    k_scan_local    <<<NBUCK / 1024, 1024, 0, stream>>>(hist, local, chunksum);
    k_scan_chunk    <<<1,   256, 0, stream>>>(chunksum, chunkoff);
    k_scatter       <<<NPTS / 256, 256, 0, stream>>>(probs, local, chunkoff, cnt, bucketed);
    k_rank          <<<NPTS / 256, 256, 0, stream>>>(bucketed, hist, local, chunkoff,
                                                     probs, scal, rankscale);
    k_perm          <<<(NBAT * NPTS) / 256, 256, 0, stream>>>(
        (const float4*)pts, rankscale, (float4*)out);
}

// Round 5
// 165.660 us; speedup vs baseline: 1.0484x; 1.0484x over previous
//
#include <hip/hip_runtime.h>
#include <hip/hip_bf16.h>
#include <cstdint>

// Problem constants
#define NPTS  131072
#define NRET  65536
#define NBAT  64
#define NBUCK (1 << 18)   // buckets = top-18 bits of descending key
#define BSH   14          // d >> 14 -> bucket

// Monotone map f32 -> u32 such that ascending u32 == DESCENDING float value.
__device__ __forceinline__ unsigned int desc_key(float w) {
    unsigned int b = __float_as_uint(w);
    unsigned int s = b ^ ((unsigned int)((int)b >> 31) | 0x80000000u); // ascending
    return ~s;                                                        // descending
}

// Zero 2 MiB (hist + cnt) with uint4 stores: 512 blocks x 256 threads x 16 B.
// (hipMemsetAsync's fillBufferAligned took 76 us at 27 GB/s for this 2 MB.)
__global__ void k_zero(uint4* __restrict__ p) {
    int t = blockIdx.x * 256 + threadIdx.x;
    p[t] = make_uint4(0u, 0u, 0u, 0u);
}

// ---------- max reduction (exact, order-independent) ----------
__global__ void k_pmax(const float* __restrict__ w, float* __restrict__ pmax) {
    __shared__ float sm[256];
    int tid = threadIdx.x;
    float m = -3.402823466e38f;
    for (int i = blockIdx.x * 256 + tid; i < NPTS; i += gridDim.x * 256)
        m = fmaxf(m, w[i]);
    sm[tid] = m; __syncthreads();
    for (int off = 128; off > 0; off >>= 1) {
        if (tid < off) sm[tid] = fmaxf(sm[tid], sm[tid + off]);
        __syncthreads();
    }
    if (tid == 0) pmax[blockIdx.x] = sm[0];
}

__global__ void k_fmax(const float* __restrict__ pmax, float* __restrict__ scal) {
    __shared__ float sm[256];
    int tid = threadIdx.x;
    sm[tid] = pmax[tid]; __syncthreads();
    for (int off = 128; off > 0; off >>= 1) {
        if (tid < off) sm[tid] = fmaxf(sm[tid], sm[tid + off]);
        __syncthreads();
    }
    if (tid == 0) scal[0] = sm[0];
}

// e_i = correctly-rounded f32 exp(f32(w_i - m)) via double; fused numpy base-128
// pairwise partial sum (8 interleaved accumulators, numpy's combine order).
__global__ void k_exp_sum(const float* __restrict__ w, const float* __restrict__ scal,
                          float* __restrict__ e_out, float* __restrict__ bs) {
    int t = blockIdx.x * 256 + threadIdx.x;       // 0..1023, 128 elems each
    const float* wp = w + (size_t)t * 128;
    float* ep = e_out + (size_t)t * 128;
    float m = scal[0];
    float r[8];
    #pragma unroll
    for (int k = 0; k < 8; ++k) {
        float e = (float)exp((double)(wp[k] - m));
        ep[k] = e; r[k] = e;
    }
    for (int i = 8; i < 128; i += 8) {
        #pragma unroll
        for (int k = 0; k < 8; ++k) {
            float e = (float)exp((double)(wp[i + k] - m));
            ep[i + k] = e; r[k] += e;
        }
    }
    bs[t] = ((r[0]+r[1])+(r[2]+r[3]))+((r[4]+r[5])+(r[6]+r[7]));
}

// Perfect binary combine tree over 1024 base sums (numpy's recursion shape).
// mode 0: dst = sum ; mode 1: dst = 1/(sum + 1e-6)
__global__ void k_tree(const float* __restrict__ bs, float* __restrict__ dst, int mode) {
    __shared__ float sm[1024];
    int tid = threadIdx.x;
    sm[tid] = bs[tid]; __syncthreads();
    for (int n = 512; n >= 1; n >>= 1) {
        float v = 0.0f;
        if (tid < n) v = sm[2*tid] + sm[2*tid+1];
        __syncthreads();
        if (tid < n) sm[tid] = v;
        __syncthreads();
    }
    if (tid == 0) dst[0] = mode ? (1.0f / (sm[0] + 1e-6f)) : sm[0];
}

// p_i = e_i / Z (IEEE f32 div, matches np); histogram; fused base-128 sum of p.
__global__ void k_prob_hist_sum(float* __restrict__ probs, const float* __restrict__ scal,
                                unsigned int* __restrict__ hist, float* __restrict__ bs2) {
    int t = blockIdx.x * 256 + threadIdx.x;       // 0..1023, 128 elems each
    float* pp = probs + (size_t)t * 128;
    float Z = scal[1];
    float r[8];
    #pragma unroll
    for (int k = 0; k < 8; ++k) {
        float pv = pp[k] / Z;
        pp[k] = pv; r[k] = pv;
        atomicAdd(&hist[desc_key(pv) >> BSH], 1u);
    }
    for (int i = 8; i < 128; i += 8) {
        #pragma unroll
        for (int k = 0; k < 8; ++k) {
            float pv = pp[i + k] / Z;
            pp[i + k] = pv; r[k] += pv;
            atomicAdd(&hist[desc_key(pv) >> BSH], 1u);
        }
    }
    bs2[t] = ((r[0]+r[1])+(r[2]+r[3]))+((r[4]+r[5])+(r[6]+r[7]));
}

// ---------- bucket ranking sort ----------
__global__ void k_scan_local(const unsigned int* __restrict__ hist,
                             unsigned int* __restrict__ local,
                             unsigned int* __restrict__ chunksum) {
    __shared__ unsigned int sm[1024];
    int tid = threadIdx.x;
    int g = blockIdx.x * 1024 + tid;
    unsigned int v = hist[g];
    sm[tid] = v; __syncthreads();
    for (int off = 1; off < 1024; off <<= 1) {
        unsigned int t = (tid >= off) ? sm[tid - off] : 0u;
        __syncthreads();
        sm[tid] += t;
        __syncthreads();
    }
    local[g] = sm[tid] - v;                  // exclusive within chunk
    if (tid == 1023) chunksum[blockIdx.x] = sm[1023];
}

__global__ void k_scan_chunk(const unsigned int* __restrict__ chunksum,
                             unsigned int* __restrict__ chunkoff) {
    __shared__ unsigned int sm[256];
    int tid = threadIdx.x;
    unsigned int v = chunksum[tid];
    sm[tid] = v; __syncthreads();
    for (int off = 1; off < 256; off <<= 1) {
        unsigned int t = (tid >= off) ? sm[tid - off] : 0u;
        __syncthreads();
        sm[tid] += t;
        __syncthreads();
    }
    chunkoff[tid] = sm[tid] - v;
}

// Scatter unique key (desc_prob_bits<<17)|idx into its bucket segment.
__global__ void k_scatter(const float* __restrict__ probs,
                          const unsigned int* __restrict__ local,
                          const unsigned int* __restrict__ chunkoff,
                          unsigned int* __restrict__ cnt,
                          unsigned long long* __restrict__ bucketed) {
    int i = blockIdx.x * 256 + threadIdx.x;
    unsigned int d = desc_key(probs[i]);
    unsigned int b = d >> BSH;
    unsigned int base = chunkoff[b >> 10] + local[b];
    unsigned int off = atomicAdd(&cnt[b], 1u);
    bucketed[base + off] = ((unsigned long long)d << 17) | (unsigned int)i;
}

// Exact global rank = bucket base + (# strictly smaller keys in bucket).
// Keys unique -> permutation -> deterministic. Equal probs order index-asc.
// Also premultiplies the per-point scale for the gather.
__global__ void k_rank(const unsigned long long* __restrict__ bucketed,
                       const unsigned int* __restrict__ hist,
                       const unsigned int* __restrict__ local,
                       const unsigned int* __restrict__ chunkoff,
                       const float* __restrict__ probs,
                       const float* __restrict__ scal,
                       unsigned int* __restrict__ ret_idx,
                       float* __restrict__ ret_scale) {
    int p = blockIdx.x * 256 + threadIdx.x;
    unsigned long long kk = bucketed[p];
    unsigned int b = (unsigned int)(kk >> 31);        // (d<<17)>>31 == d>>14
    unsigned int start = chunkoff[b >> 10] + local[b];
    unsigned int len = hist[b];
    unsigned int c = 0;
    for (unsigned int q = start; q < start + len; ++q)
        c += (bucketed[q] < kk) ? 1u : 0u;
    unsigned int rank = start + c;
    if (rank < NRET) {
        unsigned int i = (unsigned int)(kk & 0x1FFFFu);
        ret_idx[rank] = i;
        ret_scale[rank] = probs[i] * scal[2];
    }
}

// ---------- final gather, batch-per-XCD swizzled ----------
// block j -> xcd v=j&7, slot s=j>>3; batch b = v + 8*(s>>8); rank block = s&255.
// All 256 blocks of a batch dispatch to one XCD consecutively, so the batch's
// 2 MiB read set stays L2-resident (4 MiB/XCD) and each line is fetched once.
// Random 16 B reads (request-rate-bound); writes fully coalesced.
// NOTE (R4 lesson): the inverted scatter-write variant (coalesced read, random
// 16 B write) measured ~2x SLOWER (~158 us) - keep randomness on the READ side.
__global__ void k_gather(const float4* __restrict__ pts,
                         const unsigned int* __restrict__ ret_idx,
                         const float* __restrict__ ret_scale,
                         float4* __restrict__ out) {
    int j = blockIdx.x;
    int v = j & 7;
    int s = j >> 3;
    int b = v + ((s >> 8) << 3);
    int r = ((s & 255) << 8) + threadIdx.x;
    unsigned int i = ret_idx[r];
    float sc = ret_scale[r];
    float4 val = pts[(size_t)b * NPTS + i];
    val.x *= sc; val.y *= sc; val.z *= sc; val.w *= sc;
    out[(size_t)b * NRET + r] = val;
}

extern "C" void kernel_launch(void* const* d_in, const int* in_sizes, int n_in,
                              void* d_out, int out_size, void* d_ws, size_t ws_size,
                              hipStream_t stream) {
    const float* pts = (const float*)d_in[0];   // [64, 131072, 4]
    const float* w   = (const float*)d_in[1];   // [131072]
    float* out = (float*)d_out;

    char* ws = (char*)d_ws;
    unsigned int* hist      = (unsigned int*)(ws + 0);                 // 1 MB
    unsigned int* cnt       = (unsigned int*)(ws + (1 << 20));         // 1 MB
    unsigned int* local     = (unsigned int*)(ws + (2 << 20));         // 1 MB
    unsigned int* chunksum  = (unsigned int*)(ws + (3 << 20));         // 1 KB
    unsigned int* chunkoff  = (unsigned int*)(ws + (3 << 20) + 4096);  // 1 KB
    float*        pmax      = (float*)(ws + (3 << 20) + 8192);         // 1 KB
    float*        scal      = (float*)(ws + (3 << 20) + 12288);        // m, Z, inv
    float*        bs        = (float*)(ws + (3 << 20) + 16384);        // 4 KB
    float*        bs2       = (float*)(ws + (3 << 20) + 24576);        // 4 KB
    float*        ret_scale = (float*)(ws + (3 << 20) + 32768);        // 256 KB
    float*        probs     = (float*)(ws + (3 << 20) + (1 << 19) + (1 << 18)); // 512 KB
    unsigned long long* bucketed = (unsigned long long*)(ws + (5 << 20)); // 1 MB
    unsigned int* ret_idx   = (unsigned int*)(ws + (6 << 20));         // 256 KB

    k_zero          <<<512, 256, 0, stream>>>((uint4*)ws);           // hist + cnt
    k_pmax          <<<256, 256, 0, stream>>>(w, pmax);
    k_fmax          <<<1,   256, 0, stream>>>(pmax, scal);
    k_exp_sum       <<<4,   256, 0, stream>>>(w, scal, probs, bs);   // probs = e
    k_tree          <<<1,  1024, 0, stream>>>(bs, &scal[1], 0);      // Z
    k_prob_hist_sum <<<4,   256, 0, stream>>>(probs, scal, hist, bs2); // probs = p
    k_tree          <<<1,  1024, 0, stream>>>(bs2, &scal[2], 1);     // 1/(S+1e-6)
    k_scan_local    <<<NBUCK / 1024, 1024, 0, stream>>>(hist, local, chunksum);
    k_scan_chunk    <<<1,   256, 0, stream>>>(chunksum, chunkoff);
    k_scatter       <<<NPTS / 256, 256, 0, stream>>>(probs, local, chunkoff, cnt, bucketed);
    k_rank          <<<NPTS / 256, 256, 0, stream>>>(bucketed, hist, local, chunkoff,
                                                     probs, scal, ret_idx, ret_scale);
    k_gather        <<<(NBAT * NRET) / 256, 256, 0, stream>>>(
        (const float4*)pts, ret_idx, ret_scale, (float4*)out);
}

// Round 6
// 124.413 us; speedup vs baseline: 1.3960x; 1.3315x over previous
//
#include <hip/hip_runtime.h>
#include <hip/hip_bf16.h>
#include <cstdint>

// Problem constants
#define NPTS  131072
#define NRET  65536
#define NBAT  64
#define NBUCK (1 << 18)   // buckets = top-18 bits of descending key
#define BSH   14          // d >> 14 -> bucket

// Monotone map f32 -> u32 such that ascending u32 == DESCENDING float value.
__device__ __forceinline__ unsigned int desc_key(float w) {
    unsigned int b = __float_as_uint(w);
    unsigned int s = b ^ ((unsigned int)((int)b >> 31) | 0x80000000u); // ascending
    return ~s;                                                        // descending
}

// Zero 2 MiB (hist + cnt) with uint4 stores: 512 blocks x 256 threads x 16 B.
__global__ void k_zero(uint4* __restrict__ p) {
    int t = blockIdx.x * 256 + threadIdx.x;
    p[t] = make_uint4(0u, 0u, 0u, 0u);
}

// ---------- max reduction (exact, order-independent) ----------
__global__ void k_pmax(const float* __restrict__ w, float* __restrict__ pmax) {
    __shared__ float sm[256];
    int tid = threadIdx.x;
    float m = -3.402823466e38f;
    for (int i = blockIdx.x * 256 + tid; i < NPTS; i += gridDim.x * 256)
        m = fmaxf(m, w[i]);
    sm[tid] = m; __syncthreads();
    for (int off = 128; off > 0; off >>= 1) {
        if (tid < off) sm[tid] = fmaxf(sm[tid], sm[tid + off]);
        __syncthreads();
    }
    if (tid == 0) pmax[blockIdx.x] = sm[0];
}

// e_i = correctly-rounded f32 exp(f32(w_i - m)) via double. One thread per
// numpy 8-accumulator LANE of each 128-elem base block: lane k of base block
// sums e[k], e[k+8], ..., e[k+120] in order (numpy's r[k]); 8 lanes combined
// pairwise in numpy's order via LDS. Final max over pmax[256] done in-block.
// 32 blocks x 256 threads = 8192 tasks = 1024 base blocks x 8 lanes.
__global__ void k_exp_sum(const float* __restrict__ w, const float* __restrict__ pmax,
                          float* __restrict__ e_out, float* __restrict__ bs) {
    __shared__ float smm[256];
    __shared__ float smr[256];
    int tid = threadIdx.x;
    // block-local final max of the 256 partial maxes (exact, order-independent)
    smm[tid] = pmax[tid]; __syncthreads();
    for (int off = 128; off > 0; off >>= 1) {
        if (tid < off) smm[tid] = fmaxf(smm[tid], smm[tid + off]);
        __syncthreads();
    }
    float m = smm[0];
    int task = blockIdx.x * 256 + tid;       // 0..8191
    int base = task >> 3;                    // base block 0..1023
    int k    = task & 7;                     // accumulator lane
    const float* wp = w + (size_t)base * 128;
    float* ep = e_out + (size_t)base * 128;
    float r = 0.0f;
    #pragma unroll
    for (int i = 0; i < 128; i += 8) {       // numpy order within lane
        float e = (float)exp((double)(wp[i + k] - m));
        ep[i + k] = e;
        r += e;
    }
    smr[tid] = r; __syncthreads();
    if (k == 0)                               // numpy pairwise combine of 8 lanes
        bs[base] = ((smr[tid]+smr[tid+1])+(smr[tid+2]+smr[tid+3]))
                 + ((smr[tid+4]+smr[tid+5])+(smr[tid+6]+smr[tid+7]));
}

// Perfect binary combine tree over 1024 base sums (numpy's recursion shape).
// mode 0: dst = sum ; mode 1: dst = 1/(sum + 1e-6)
__global__ void k_tree(const float* __restrict__ bs, float* __restrict__ dst, int mode) {
    __shared__ float sm[1024];
    int tid = threadIdx.x;
    sm[tid] = bs[tid]; __syncthreads();
    for (int n = 512; n >= 1; n >>= 1) {
        float v = 0.0f;
        if (tid < n) v = sm[2*tid] + sm[2*tid+1];
        __syncthreads();
        if (tid < n) sm[tid] = v;
        __syncthreads();
    }
    if (tid == 0) dst[0] = mode ? (1.0f / (sm[0] + 1e-6f)) : sm[0];
}

// p_i = e_i / Z (IEEE f32 div, matches np); histogram; numpy base-128 sum of p.
// Same 8192-task lane structure as k_exp_sum.
__global__ void k_prob_hist_sum(float* __restrict__ probs, const float* __restrict__ scal,
                                unsigned int* __restrict__ hist, float* __restrict__ bs2) {
    __shared__ float smr[256];
    int tid = threadIdx.x;
    int task = blockIdx.x * 256 + tid;
    int base = task >> 3;
    int k    = task & 7;
    float* pp = probs + (size_t)base * 128;
    float Z = scal[1];
    float r = 0.0f;
    #pragma unroll
    for (int i = 0; i < 128; i += 8) {
        float pv = pp[i + k] / Z;
        pp[i + k] = pv;
        r += pv;
        atomicAdd(&hist[desc_key(pv) >> BSH], 1u);
    }
    smr[tid] = r; __syncthreads();
    if (k == 0)
        bs2[base] = ((smr[tid]+smr[tid+1])+(smr[tid+2]+smr[tid+3]))
                  + ((smr[tid+4]+smr[tid+5])+(smr[tid+6]+smr[tid+7]));
}

// ---------- bucket ranking sort ----------
// 256 blocks x 256 threads; each thread owns 4 consecutive buckets (uint4).
// Block-level exclusive scan (any exact scan is fine - integers).
__global__ void k_scan_local(const unsigned int* __restrict__ hist,
                             unsigned int* __restrict__ local,
                             unsigned int* __restrict__ chunksum) {
    __shared__ unsigned int sm[256];
    int tid = threadIdx.x;
    int g0 = (blockIdx.x * 256 + tid) * 4;
    uint4 h = *(const uint4*)&hist[g0];
    unsigned int s = h.x + h.y + h.z + h.w;
    sm[tid] = s; __syncthreads();
    for (int off = 1; off < 256; off <<= 1) {
        unsigned int t = (tid >= off) ? sm[tid - off] : 0u;
        __syncthreads();
        sm[tid] += t;
        __syncthreads();
    }
    unsigned int excl = sm[tid] - s;
    uint4 o;
    o.x = excl; o.y = excl + h.x; o.z = o.y + h.y; o.w = o.z + h.z;
    *(uint4*)&local[g0] = o;
    if (tid == 255) chunksum[blockIdx.x] = sm[255];
}

__global__ void k_scan_chunk(const unsigned int* __restrict__ chunksum,
                             unsigned int* __restrict__ chunkoff) {
    __shared__ unsigned int sm[256];
    int tid = threadIdx.x;
    unsigned int v = chunksum[tid];
    sm[tid] = v; __syncthreads();
    for (int off = 1; off < 256; off <<= 1) {
        unsigned int t = (tid >= off) ? sm[tid - off] : 0u;
        __syncthreads();
        sm[tid] += t;
        __syncthreads();
    }
    chunkoff[tid] = sm[tid] - v;
}

// Scatter unique key (desc_prob_bits<<17)|idx into its bucket segment.
__global__ void k_scatter(const float* __restrict__ probs,
                          const unsigned int* __restrict__ local,
                          const unsigned int* __restrict__ chunkoff,
                          unsigned int* __restrict__ cnt,
                          unsigned long long* __restrict__ bucketed) {
    int i = blockIdx.x * 256 + threadIdx.x;
    unsigned int d = desc_key(probs[i]);
    unsigned int b = d >> BSH;
    unsigned int base = chunkoff[b >> 10] + local[b];
    unsigned int off = atomicAdd(&cnt[b], 1u);
    bucketed[base + off] = ((unsigned long long)d << 17) | (unsigned int)i;
}

// Exact global rank = bucket base + (# strictly smaller keys in bucket).
// Keys unique -> permutation -> deterministic. Equal probs order index-asc.
// Writes {src index, premultiplied scale} at slot [rank].
__global__ void k_rank(const unsigned long long* __restrict__ bucketed,
                       const unsigned int* __restrict__ hist,
                       const unsigned int* __restrict__ local,
                       const unsigned int* __restrict__ chunkoff,
                       const float* __restrict__ probs,
                       const float* __restrict__ scal,
                       uint2* __restrict__ ret_rs) {
    int p = blockIdx.x * 256 + threadIdx.x;
    unsigned long long kk = bucketed[p];
    unsigned int b = (unsigned int)(kk >> 31);        // (d<<17)>>31 == d>>14
    unsigned int start = chunkoff[b >> 10] + local[b];
    unsigned int len = hist[b];
    unsigned int c = 0;
    for (unsigned int q = start; q < start + len; ++q)
        c += (bucketed[q] < kk) ? 1u : 0u;
    unsigned int rank = start + c;
    if (rank < NRET) {
        unsigned int i = (unsigned int)(kk & 0x1FFFFu);
        ret_rs[rank] = make_uint2(i, __float_as_uint(probs[i] * scal[2]));
    }
}

// ---------- final gather: 8 independent gathers per thread (MLP) ----------
// 2048 blocks: xcd v=j&7, s=j>>3 (0..255), batch b=v+8*(s>>5), slot=(s&31).
// Thread covers ranks slot*2048 + tid + 256*k, k=0..7: 8 independent random
// 16 B reads in flight per thread (R5 was 1/thread -> latency-bound 1.8 TB/s).
// Batch-per-XCD swizzle keeps each batch's 2 MiB read set L2-resident.
// R4 lesson: keep randomness on the READ side (scatter-writes were 2x worse).
__global__ void k_gather(const float4* __restrict__ pts,
                         const uint2* __restrict__ ret_rs,
                         float4* __restrict__ out) {
    int j = blockIdx.x;
    int v = j & 7;
    int s = j >> 3;
    int b = v + ((s >> 5) << 3);
    int r0 = ((s & 31) << 11) + threadIdx.x;
    const float4* src = pts + (size_t)b * NPTS;
    float4* dst = out + (size_t)b * NRET;

    uint2 rs[8];
    #pragma unroll
    for (int k = 0; k < 8; ++k) rs[k] = ret_rs[r0 + (k << 8)];
    float4 val[8];
    #pragma unroll
    for (int k = 0; k < 8; ++k) val[k] = src[rs[k].x];
    #pragma unroll
    for (int k = 0; k < 8; ++k) {
        float sc = __uint_as_float(rs[k].y);
        val[k].x *= sc; val[k].y *= sc; val[k].z *= sc; val[k].w *= sc;
        dst[r0 + (k << 8)] = val[k];
    }
}

extern "C" void kernel_launch(void* const* d_in, const int* in_sizes, int n_in,
                              void* d_out, int out_size, void* d_ws, size_t ws_size,
                              hipStream_t stream) {
    const float* pts = (const float*)d_in[0];   // [64, 131072, 4]
    const float* w   = (const float*)d_in[1];   // [131072]
    float* out = (float*)d_out;

    char* ws = (char*)d_ws;
    unsigned int* hist      = (unsigned int*)(ws + 0);                 // 1 MB
    unsigned int* cnt       = (unsigned int*)(ws + (1 << 20));         // 1 MB
    unsigned int* local     = (unsigned int*)(ws + (2 << 20));         // 1 MB
    unsigned int* chunksum  = (unsigned int*)(ws + (3 << 20));         // 1 KB
    unsigned int* chunkoff  = (unsigned int*)(ws + (3 << 20) + 4096);  // 1 KB
    float*        pmax      = (float*)(ws + (3 << 20) + 8192);         // 1 KB
    float*        scal      = (float*)(ws + (3 << 20) + 12288);        // m, Z, inv
    float*        bs        = (float*)(ws + (3 << 20) + 16384);        // 4 KB
    float*        bs2       = (float*)(ws + (3 << 20) + 24576);        // 4 KB
    float*        probs     = (float*)(ws + (3 << 20) + (1 << 19));    // 512 KB @3.5MB
    unsigned long long* bucketed = (unsigned long long*)(ws + (4 << 20)); // 1 MB
    uint2*        ret_rs    = (uint2*)(ws + (5 << 20));                // 512 KB

    k_zero          <<<512, 256, 0, stream>>>((uint4*)ws);           // hist + cnt
    k_pmax          <<<256, 256, 0, stream>>>(w, pmax);
    k_exp_sum       <<<32,  256, 0, stream>>>(w, pmax, probs, bs);   // probs = e
    k_tree          <<<1,  1024, 0, stream>>>(bs, &scal[1], 0);      // Z
    k_prob_hist_sum <<<32,  256, 0, stream>>>(probs, scal, hist, bs2); // probs = p
    k_tree          <<<1,  1024, 0, stream>>>(bs2, &scal[2], 1);     // 1/(S+1e-6)
    k_scan_local    <<<256, 256, 0, stream>>>(hist, local, chunksum);
    k_scan_chunk    <<<1,   256, 0, stream>>>(chunksum, chunkoff);
    k_scatter       <<<NPTS / 256, 256, 0, stream>>>(probs, local, chunkoff, cnt, bucketed);
    k_rank          <<<NPTS / 256, 256, 0, stream>>>(bucketed, hist, local, chunkoff,
                                                     probs, scal, ret_rs);
    k_gather        <<<2048, 256, 0, stream>>>((const float4*)pts, ret_rs, (float4*)out);
}